// Round 2
// baseline (892.247 us; speedup 1.0000x reference)
//
#include <hip/hip_runtime.h>

// LSTM: B=512, T=512, I=128, H=50, O=10, fp32.
// R6: lstm_rec rebuilt from R5 post-mortem.
//  - R5's per-iteration `asm("s_waitcnt lgkmcnt(0)":::"memory")` was a full
//    compiler memory barrier: whh16 re-fetched every step + no scheduling
//    across it -> 3178 cyc/step. REMOVED ENTIRELY: single-wave DS pipe is
//    HW in-order (R5 proved correctness: passed, same absmax), and the
//    within-thread may-alias of hbuf[k] vs hbuf[j*8+..] already forbids
//    compiler reordering/caching. No barrier, no waitcnt -> prefetch loads
//    finally stay in flight (R4's vmcnt(0) drain was its 1294cyc/step).
//  - R5's weight pin failed (VGPR=76 < 112 needed): 7 asms x 4 operands let
//    the allocator keep only 16 live at a time. Now ONE asm with all 28
//    "+v" operands INSIDE the loop: values are loop-carried through an
//    opaque asm -> remat impossible, in-loop spill too expensive -> resident.
//  - xp layout [b][t][unit*4+gate] kept (one dwordx2/step), bias pre-added.

#define BB 512
#define TT 512
#define II 128
#define HH 50
#define GG 200   // 4*H

typedef _Float16 half2v __attribute__((ext_vector_type(2)));
typedef _Float16 half4v __attribute__((ext_vector_type(4)));
typedef _Float16 half8v __attribute__((ext_vector_type(8)));
typedef float float4v __attribute__((ext_vector_type(4)));

#if defined(__has_builtin)
#if __has_builtin(__builtin_amdgcn_fdot2)
#define HAVE_FDOT2 1
#endif
#endif

__device__ __forceinline__ float fdot2f(half2v a, half2v b, float c) {
#ifdef HAVE_FDOT2
    return __builtin_amdgcn_fdot2(a, b, c, false);
#else
    return c + (float)a[0] * (float)b[0] + (float)a[1] * (float)b[1];
#endif
}

__device__ __forceinline__ float fsig(float x) {
    return 1.f / (1.f + __expf(-x));
}
__device__ __forceinline__ float ftanh(float x) {
    return 2.f * fsig(2.f * x) - 1.f;
}

// ---------------- Kernel 0: prep (once per launch) ----------------
// Gate permutation: gp = unit*4 + gate  <->  orig g = gate*50 + unit.
// wfrags: W_ih rows in PERMUTED order as f16 MFMA B-fragments
//         [nt 13][kc 4][lane 64][j 8]
// whh16:  W_hh rows padded to 56 f16, ORIGINAL order  [g 200][56]
// biasv:  b_ih + b_hh in PERMUTED order               [gp 200]
__global__ __launch_bounds__(256) void prep_kernel(
    const float* __restrict__ W_ih, const float* __restrict__ W_hh,
    const float* __restrict__ b_ih, const float* __restrict__ b_hh,
    _Float16* __restrict__ wfrags, _Float16* __restrict__ whh16,
    float* __restrict__ biasv)
{
    int idx = blockIdx.x * 256 + threadIdx.x;
    if (idx < 3328) {                       // 13*4*64 fragment slots
        int lane = idx & 63, kc = (idx >> 6) & 3, nt = idx >> 8;
        int gp = nt * 16 + (lane & 15);     // permuted gate index
        int k0 = kc * 32 + ((lane >> 4) & 3) * 8;
        half8v v;
        if (gp < GG) {
            int u = gp >> 2, j = gp & 3;
            const float* wr = W_ih + (size_t)(j * HH + u) * II + k0;
            #pragma unroll
            for (int q = 0; q < 8; ++q) v[q] = (_Float16)wr[q];
        } else {
            #pragma unroll
            for (int q = 0; q < 8; ++q) v[q] = (_Float16)0.f;
        }
        *(half8v*)(wfrags + (size_t)idx * 8) = v;
    } else if (idx < 3328 + 2800) {         // 200 rows * 14 quads
        int r = idx - 3328;
        int g = r / 14, j4 = r % 14;
        #pragma unroll
        for (int j = 0; j < 4; ++j) {
            int hidx = j4 * 4 + j;
            whh16[g * 56 + hidx] = (hidx < HH) ? (_Float16)W_hh[g * HH + hidx]
                                               : (_Float16)0.f;
        }
    } else if (idx < 3328 + 2800 + GG) {
        int gp = idx - 6128;
        int u = gp >> 2, j = gp & 3;
        biasv[gp] = b_ih[j * HH + u] + b_hh[j * HH + u];
    }
}

// ---------------- Kernel 1: xproj via MFMA, t-major tiles ----------------
// Block = (b, t-tile of 64). A = x[b][t0:t0+64][0:128] (contiguous 32KB).
// Output xp16[b][t - chunk][gp] f16, bias pre-added, coalesced 16B stores.
__global__ __launch_bounds__(256) void xproj_mfma(
    const float* __restrict__ x, const _Float16* __restrict__ wfrags,
    const float* __restrict__ biasv, _Float16* __restrict__ xp16,
    int t0, int tsh)
{
    __shared__ __align__(16) _Float16 afrag[4 * 4 * 64 * 8];  // 16 KB
    __shared__ __align__(16) _Float16 dtile[64 * GG];         // 25.6 KB
    const int tid = threadIdx.x;
    const int b = blockIdx.x >> tsh;
    const int tt = blockIdx.x & ((1 << tsh) - 1);
    const int trow0 = t0 + tt * 64;         // global t of tile row 0

    // Stage A: thread owns one fragment slot (16B): 2 float4 loads, 1 b128 write.
    // Wave reads 16 rows x 128B contiguous each -> full-cacheline coalescing.
    const float* xb = x + ((size_t)b * TT + trow0) * II;
    #pragma unroll
    for (int it = 0; it < 4; ++it) {
        int s = it * 256 + tid;             // slot in [0,1024)
        int l = s & 63, kc = (s >> 6) & 3, wq = s >> 8;
        int row = wq * 16 + (l & 15);
        int k0 = kc * 32 + ((l >> 4) & 3) * 8;
        const float4 v0 = *(const float4*)(xb + (size_t)row * II + k0);
        const float4 v1 = *(const float4*)(xb + (size_t)row * II + k0 + 4);
        half8v p;
        p[0] = (_Float16)v0.x; p[1] = (_Float16)v0.y;
        p[2] = (_Float16)v0.z; p[3] = (_Float16)v0.w;
        p[4] = (_Float16)v1.x; p[5] = (_Float16)v1.y;
        p[6] = (_Float16)v1.z; p[7] = (_Float16)v1.w;
        *(half8v*)(afrag + (size_t)s * 8) = p;
    }
    __syncthreads();

    const int w = tid >> 6;
    const int l = tid & 63;
    float4v acc[13];
    #pragma unroll
    for (int nt = 0; nt < 13; ++nt) acc[nt] = (float4v){0.f, 0.f, 0.f, 0.f};

    #pragma unroll
    for (int kc = 0; kc < 4; ++kc) {
        half8v a = *(half8v*)(afrag + (size_t)(((w * 4 + kc) * 64) + l) * 8);
        #pragma unroll
        for (int nt = 0; nt < 13; ++nt) {
            half8v bf = *(const half8v*)(wfrags + (size_t)(((nt * 4 + kc) * 64) + l) * 8);
            acc[nt] = __builtin_amdgcn_mfma_f32_16x16x32_f16(a, bf, acc[nt], 0, 0, 0);
        }
    }

    // D restage: col=lane&15 (permuted gate), row=(lane>>4)*4+reg (t-row).
    const int colb = l & 15, rq = l >> 4;
    #pragma unroll
    for (int nt = 0; nt < 13; ++nt) {
        int g = nt * 16 + colb;
        if (g < GG) {
            float bs = biasv[g];
            #pragma unroll
            for (int reg = 0; reg < 4; ++reg)
                dtile[(w * 16 + rq * 4 + reg) * GG + g] = (_Float16)(acc[nt][reg] + bs);
        }
    }
    __syncthreads();

    // Coalesced writeout: 64*200 f16 = 1600 x 16B contiguous.
    _Float16* outp = xp16 + ((size_t)b * (64 << tsh) + (size_t)tt * 64) * GG;
    #pragma unroll
    for (int it = 0; it < 7; ++it) {
        int idx = it * 256 + tid;
        if (idx < 1600) {
            float4v v = *(const float4v*)(dtile + (size_t)idx * 8);
            *(float4v*)(outp + (size_t)idx * 8) = v;
        }
    }
}

// ---------------- Kernel 2: recurrence (barrier-free, asm-free loop) ------
__global__ __launch_bounds__(64, 1) void lstm_rec(
    const _Float16* __restrict__ xp16, const _Float16* __restrict__ whh16,
    float* __restrict__ hs, float* __restrict__ cs, int Tc, int first)
{
    __shared__ __align__(16) _Float16 hbuf[64];
    const int b = blockIdx.x;
    const int k = threadIdx.x;
    const int kk = (k < HH) ? k : 0;

    // W_hh rows for unit kk, 4 gates (f16-packed, 112 VGPRs).
    float4v wr0[7], wr1[7], wr2[7], wr3[7];
    #pragma unroll
    for (int j = 0; j < 7; ++j) {
        wr0[j] = *(const float4v*)(whh16 + (size_t)(kk      ) * 56 + j * 8);
        wr1[j] = *(const float4v*)(whh16 + (size_t)(kk +  50) * 56 + j * 8);
        wr2[j] = *(const float4v*)(whh16 + (size_t)(kk + 100) * 56 + j * 8);
        wr3[j] = *(const float4v*)(whh16 + (size_t)(kk + 150) * 56 + j * 8);
    }

    float c = 0.f;
    _Float16 hinit = (_Float16)0.f;
    if (!first && k < HH) {
        c = cs[b * HH + k];
        hinit = (_Float16)hs[b * HH + k];
    }
    hbuf[k] = hinit;
    __syncthreads();   // once, before the loop (init visibility)

    // xp: [b][t][unit*4+gate] -> one 8B load per step, contiguous 400B/step.
    const _Float16* xpb = xp16 + (size_t)b * Tc * GG + kk * 4;
    half4v pv[4];
    #pragma unroll
    for (int d = 0; d < 4; ++d) {
        int td = (d < Tc) ? d : (Tc - 1);
        pv[d] = *(const half4v*)(xpb + (size_t)td * GG);
    }

    float hlast = 0.f;
    #pragma unroll 4
    for (int t = 0; t < Tc; ++t) {
        // Single asm, ALL 28 weight vectors as "+v": forces 112 regs
        // simultaneously live each iteration; values loop-carry through an
        // opaque asm -> remat from global impossible, spill in-loop too
        // costly -> allocator keeps them resident. Emits no instructions,
        // no memory clobber -> scheduler stays free.
        asm volatile("" :
            "+v"(wr0[0]), "+v"(wr0[1]), "+v"(wr0[2]), "+v"(wr0[3]),
            "+v"(wr0[4]), "+v"(wr0[5]), "+v"(wr0[6]),
            "+v"(wr1[0]), "+v"(wr1[1]), "+v"(wr1[2]), "+v"(wr1[3]),
            "+v"(wr1[4]), "+v"(wr1[5]), "+v"(wr1[6]),
            "+v"(wr2[0]), "+v"(wr2[1]), "+v"(wr2[2]), "+v"(wr2[3]),
            "+v"(wr2[4]), "+v"(wr2[5]), "+v"(wr2[6]),
            "+v"(wr3[0]), "+v"(wr3[1]), "+v"(wr3[2]), "+v"(wr3[3]),
            "+v"(wr3[4]), "+v"(wr3[5]), "+v"(wr3[6]));

        const int s = t & 3;
        half4v p = pv[s];
        float aI = (float)p[0];
        float aF = (float)p[1];
        float aG = (float)p[2];
        float aO = (float)p[3];

        // refill slot s for t+4; stays in flight (no barrier, no drain)
        {
            int tn = t + 4; if (tn >= Tc) tn = Tc - 1;
            pv[s] = *(const half4v*)(xpb + (size_t)tn * GG);
        }

        // h broadcast read. Single-wave: DS pipe is in-order (RAW vs the
        // previous iteration's write is a HW-ordered same-wave hazard), and
        // hbuf[k] (runtime k) may-alias these reads -> compiler keeps order
        // and cannot cache hbuf in registers. No barrier/waitcnt needed.
        half8v hv[7];
        #pragma unroll
        for (int j = 0; j < 7; ++j) hv[j] = *(half8v*)(hbuf + j * 8);

        #pragma unroll
        for (int j = 0; j < 7; ++j) {
            half2v* hp = (half2v*)&hv[j];
            const half2v* w0 = (const half2v*)&wr0[j];
            const half2v* w1 = (const half2v*)&wr1[j];
            const half2v* w2 = (const half2v*)&wr2[j];
            const half2v* w3 = (const half2v*)&wr3[j];
            #pragma unroll
            for (int q = 0; q < 4; ++q) {
                half2v hq = hp[q];
                aI = fdot2f(hq, w0[q], aI);
                aF = fdot2f(hq, w1[q], aF);
                aG = fdot2f(hq, w2[q], aG);
                aO = fdot2f(hq, w3[q], aO);
            }
        }
        float ii = fsig(aI), ff = fsig(aF), gg2 = ftanh(aG), oo = fsig(aO);
        c = ff * c + ii * gg2;
        float hn = oo * ftanh(c);
        if (k < HH) hbuf[k] = (_Float16)hn;
        hlast = hn;
    }
    if (k < HH) {
        hs[b * HH + k] = hlast;
        cs[b * HH + k] = c;
    }
}

// ---------------- Kernel 3: FC epilogue ----------------
__global__ __launch_bounds__(256) void fc_kernel(
    const float* __restrict__ hs, const float* __restrict__ W_fc,
    const float* __restrict__ b_fc, float* __restrict__ out)
{
    int idx = blockIdx.x * blockDim.x + threadIdx.x;   // 512*10
    if (idx < BB * 10) {
        int b = idx / 10, o = idx % 10;
        float a = b_fc[o];
        #pragma unroll
        for (int kx = 0; kx < HH; ++kx)
            a += hs[b * HH + kx] * W_fc[o * HH + kx];
        out[idx] = a;
    }
}

extern "C" void kernel_launch(void* const* d_in, const int* in_sizes, int n_in,
                              void* d_out, int out_size, void* d_ws, size_t ws_size,
                              hipStream_t stream)
{
    const float* x    = (const float*)d_in[0];
    const float* W_ih = (const float*)d_in[1];
    const float* W_hh = (const float*)d_in[2];
    const float* b_ih = (const float*)d_in[3];
    const float* b_hh = (const float*)d_in[4];
    const float* W_fc = (const float*)d_in[5];
    const float* b_fc = (const float*)d_in[6];
    float* out = (float*)d_out;
    char* wsb = (char*)d_ws;

    const size_t hs_b = (size_t)BB * HH * sizeof(float);        // 102400
    const size_t wfrags_b = (size_t)13 * 4 * 64 * 8 * 2;        // 53248
    const size_t whh_b = (size_t)GG * 56 * 2;                   // 22400
    const size_t bias_b = 1024;
    const size_t fixed_b = 2 * hs_b + wfrags_b + whh_b + bias_b;

    int Tc = TT;
    while (Tc > 64 && (size_t)BB * Tc * GG * 2 + fixed_b > ws_size)
        Tc >>= 1;
    int tsh = 0; { int v = Tc >> 6; while (v > 1) { v >>= 1; ++tsh; } }

    _Float16* xp16 = (_Float16*)wsb;
    char* p = wsb + (size_t)BB * Tc * GG * 2;
    float* hsbuf = (float*)p;            p += hs_b;
    float* csbuf = (float*)p;            p += hs_b;
    _Float16* wfrags = (_Float16*)p;     p += wfrags_b;
    _Float16* whh16 = (_Float16*)p;      p += whh_b;
    float* biasv = (float*)p;

    prep_kernel<<<25, 256, 0, stream>>>(W_ih, W_hh, b_ih, b_hh, wfrags, whh16, biasv);

    const int nch = TT / Tc;
    for (int j = 0; j < nch; ++j) {
        xproj_mfma<<<BB * (Tc >> 6), 256, 0, stream>>>(x, wfrags, biasv, xp16, j * Tc, tsh);
        lstm_rec<<<BB, 64, 0, stream>>>(xp16, whh16, hsbuf, csbuf, Tc, j == 0);
    }
    fc_kernel<<<(BB * 10 + 255) / 256, 256, 0, stream>>>(hsbuf, W_fc, b_fc, out);
}

// Round 3
// 472.744 us; speedup vs baseline: 1.8874x; 1.8874x over previous
//
#include <hip/hip_runtime.h>

// LSTM: B=512, T=512, I=128, H=50, O=10, fp32.
// R7: lstm_rec — kill the per-step weight reloads (R5/R6: 28 JIT 16B loads
//     x ~110cyc serialized = 3150 cyc/step, VALUBusy 22%, VGPR=76 proves
//     weights were never resident).
//  - amdgpu_waves_per_eu(1,1): launch_bounds only sets MIN waves/EU; the
//    scheduler still TARGETS high occupancy and sinks invariant loads into
//    the loop. Max=1 relaxes the pressure heuristic -> 112 weight VGPRs can
//    stay resident (budget 512).
//  - Defense in depth: weights staged to padded LDS [200][58] f16 (29-word
//    row stride, conflict-free for 50-lane strided ds_read_b128). If the
//    compiler still sinks the weight loads, they become pipelined ~120cyc
//    LDS reads (counted lgkmcnt), not serialized L2 round trips.
//  - No inline asm at all. No in-loop barrier (single-wave DS RAW is HW
//    in-order; correctness proven by R5/R6 passing with same absmax).
//  - xp layout [b][t][unit*4+gate] kept: one 8B load/step, 4-deep prefetch.

#define BB 512
#define TT 512
#define II 128
#define HH 50
#define GG 200   // 4*H

typedef _Float16 half2v __attribute__((ext_vector_type(2)));
typedef _Float16 half4v __attribute__((ext_vector_type(4)));
typedef _Float16 half8v __attribute__((ext_vector_type(8)));
typedef float float4v __attribute__((ext_vector_type(4)));

#if defined(__has_builtin)
#if __has_builtin(__builtin_amdgcn_fdot2)
#define HAVE_FDOT2 1
#endif
#endif

__device__ __forceinline__ float fdot2f(half2v a, half2v b, float c) {
#ifdef HAVE_FDOT2
    return __builtin_amdgcn_fdot2(a, b, c, false);
#else
    return c + (float)a[0] * (float)b[0] + (float)a[1] * (float)b[1];
#endif
}

__device__ __forceinline__ float fsig(float x) {
    return 1.f / (1.f + __expf(-x));
}
__device__ __forceinline__ float ftanh(float x) {
    return 2.f * fsig(2.f * x) - 1.f;
}

// ---------------- Kernel 0: prep (once per launch) ----------------
// Gate permutation: gp = unit*4 + gate  <->  orig g = gate*50 + unit.
// wfrags: W_ih rows in PERMUTED order as f16 MFMA B-fragments
//         [nt 13][kc 4][lane 64][j 8]
// whh16:  W_hh rows padded to 56 f16, ORIGINAL order  [g 200][56]
// biasv:  b_ih + b_hh in PERMUTED order               [gp 200]
__global__ __launch_bounds__(256) void prep_kernel(
    const float* __restrict__ W_ih, const float* __restrict__ W_hh,
    const float* __restrict__ b_ih, const float* __restrict__ b_hh,
    _Float16* __restrict__ wfrags, _Float16* __restrict__ whh16,
    float* __restrict__ biasv)
{
    int idx = blockIdx.x * 256 + threadIdx.x;
    if (idx < 3328) {                       // 13*4*64 fragment slots
        int lane = idx & 63, kc = (idx >> 6) & 3, nt = idx >> 8;
        int gp = nt * 16 + (lane & 15);     // permuted gate index
        int k0 = kc * 32 + ((lane >> 4) & 3) * 8;
        half8v v;
        if (gp < GG) {
            int u = gp >> 2, j = gp & 3;
            const float* wr = W_ih + (size_t)(j * HH + u) * II + k0;
            #pragma unroll
            for (int q = 0; q < 8; ++q) v[q] = (_Float16)wr[q];
        } else {
            #pragma unroll
            for (int q = 0; q < 8; ++q) v[q] = (_Float16)0.f;
        }
        *(half8v*)(wfrags + (size_t)idx * 8) = v;
    } else if (idx < 3328 + 2800) {         // 200 rows * 14 quads
        int r = idx - 3328;
        int g = r / 14, j4 = r % 14;
        #pragma unroll
        for (int j = 0; j < 4; ++j) {
            int hidx = j4 * 4 + j;
            whh16[g * 56 + hidx] = (hidx < HH) ? (_Float16)W_hh[g * HH + hidx]
                                               : (_Float16)0.f;
        }
    } else if (idx < 3328 + 2800 + GG) {
        int gp = idx - 6128;
        int u = gp >> 2, j = gp & 3;
        biasv[gp] = b_ih[j * HH + u] + b_hh[j * HH + u];
    }
}

// ---------------- Kernel 1: xproj via MFMA, t-major tiles ----------------
// Block = (b, t-tile of 64). A = x[b][t0:t0+64][0:128] (contiguous 32KB).
// Output xp16[b][t - chunk][gp] f16, bias pre-added, coalesced 16B stores.
__global__ __launch_bounds__(256) void xproj_mfma(
    const float* __restrict__ x, const _Float16* __restrict__ wfrags,
    const float* __restrict__ biasv, _Float16* __restrict__ xp16,
    int t0, int tsh)
{
    __shared__ __align__(16) _Float16 afrag[4 * 4 * 64 * 8];  // 16 KB
    __shared__ __align__(16) _Float16 dtile[64 * GG];         // 25.6 KB
    const int tid = threadIdx.x;
    const int b = blockIdx.x >> tsh;
    const int tt = blockIdx.x & ((1 << tsh) - 1);
    const int trow0 = t0 + tt * 64;         // global t of tile row 0

    // Stage A: thread owns one fragment slot (16B): 2 float4 loads, 1 b128 write.
    // Wave reads 16 rows x 128B contiguous each -> full-cacheline coalescing.
    const float* xb = x + ((size_t)b * TT + trow0) * II;
    #pragma unroll
    for (int it = 0; it < 4; ++it) {
        int s = it * 256 + tid;             // slot in [0,1024)
        int l = s & 63, kc = (s >> 6) & 3, wq = s >> 8;
        int row = wq * 16 + (l & 15);
        int k0 = kc * 32 + ((l >> 4) & 3) * 8;
        const float4 v0 = *(const float4*)(xb + (size_t)row * II + k0);
        const float4 v1 = *(const float4*)(xb + (size_t)row * II + k0 + 4);
        half8v p;
        p[0] = (_Float16)v0.x; p[1] = (_Float16)v0.y;
        p[2] = (_Float16)v0.z; p[3] = (_Float16)v0.w;
        p[4] = (_Float16)v1.x; p[5] = (_Float16)v1.y;
        p[6] = (_Float16)v1.z; p[7] = (_Float16)v1.w;
        *(half8v*)(afrag + (size_t)s * 8) = p;
    }
    __syncthreads();

    const int w = tid >> 6;
    const int l = tid & 63;
    float4v acc[13];
    #pragma unroll
    for (int nt = 0; nt < 13; ++nt) acc[nt] = (float4v){0.f, 0.f, 0.f, 0.f};

    #pragma unroll
    for (int kc = 0; kc < 4; ++kc) {
        half8v a = *(half8v*)(afrag + (size_t)(((w * 4 + kc) * 64) + l) * 8);
        #pragma unroll
        for (int nt = 0; nt < 13; ++nt) {
            half8v bf = *(const half8v*)(wfrags + (size_t)(((nt * 4 + kc) * 64) + l) * 8);
            acc[nt] = __builtin_amdgcn_mfma_f32_16x16x32_f16(a, bf, acc[nt], 0, 0, 0);
        }
    }

    // D restage: col=lane&15 (permuted gate), row=(lane>>4)*4+reg (t-row).
    const int colb = l & 15, rq = l >> 4;
    #pragma unroll
    for (int nt = 0; nt < 13; ++nt) {
        int g = nt * 16 + colb;
        if (g < GG) {
            float bs = biasv[g];
            #pragma unroll
            for (int reg = 0; reg < 4; ++reg)
                dtile[(w * 16 + rq * 4 + reg) * GG + g] = (_Float16)(acc[nt][reg] + bs);
        }
    }
    __syncthreads();

    // Coalesced writeout: 64*200 f16 = 1600 x 16B contiguous.
    _Float16* outp = xp16 + ((size_t)b * (64 << tsh) + (size_t)tt * 64) * GG;
    #pragma unroll
    for (int it = 0; it < 7; ++it) {
        int idx = it * 256 + tid;
        if (idx < 1600) {
            float4v v = *(const float4v*)(dtile + (size_t)idx * 8);
            *(float4v*)(outp + (size_t)idx * 8) = v;
        }
    }
}

// ---------------- Kernel 2: recurrence (single wave, LDS weights) ---------
#define WSTR 58   // padded row stride in f16 (29 words -> coprime with 32 banks)

__global__
__attribute__((amdgpu_flat_work_group_size(64, 64)))
__attribute__((amdgpu_waves_per_eu(1, 1)))
void lstm_rec(
    const _Float16* __restrict__ xp16, const _Float16* __restrict__ whh16,
    float* __restrict__ hs, float* __restrict__ cs, int Tc, int first)
{
    __shared__ __align__(16) _Float16 wlds[GG * WSTR];   // 23.2 KB
    __shared__ __align__(16) _Float16 hbuf[64];
    const int b = blockIdx.x;
    const int k = threadIdx.x;
    const int kk = (k < HH) ? k : 0;

    // Stage W_hh (22.4 KB) into padded LDS: 1400 b128 slots, 22 per lane.
    for (int s = k; s < 1400; s += 64) {
        int g = s / 7, j = s % 7;
        float4v v = *(const float4v*)(whh16 + (size_t)g * 56 + j * 8);
        *(float4v*)(wlds + (size_t)g * WSTR + j * 8) = v;
    }

    float c = 0.f;
    _Float16 hinit = (_Float16)0.f;
    if (!first && k < HH) {
        c = cs[b * HH + k];
        hinit = (_Float16)hs[b * HH + k];
    }
    hbuf[k] = hinit;
    __syncthreads();   // staging + init visibility (once)

    // Hoisted weight loads: rows kk, kk+50, kk+100, kk+150 (7 b128 each).
    // With waves_per_eu(1,1) the allocator has a 512-VGPR budget and no
    // occupancy target pressure -> these 112 VGPRs should stay resident.
    float4v wr0[7], wr1[7], wr2[7], wr3[7];
    #pragma unroll
    for (int j = 0; j < 7; ++j) {
        wr0[j] = *(const float4v*)(wlds + (size_t)(kk      ) * WSTR + j * 8);
        wr1[j] = *(const float4v*)(wlds + (size_t)(kk +  50) * WSTR + j * 8);
        wr2[j] = *(const float4v*)(wlds + (size_t)(kk + 100) * WSTR + j * 8);
        wr3[j] = *(const float4v*)(wlds + (size_t)(kk + 150) * WSTR + j * 8);
    }

    // xp: [b][t][unit*4+gate] -> one 8B load per step, 4-deep prefetch.
    const _Float16* xpb = xp16 + (size_t)b * Tc * GG + kk * 4;
    half4v pv[4];
    #pragma unroll
    for (int d = 0; d < 4; ++d) {
        int td = (d < Tc) ? d : (Tc - 1);
        pv[d] = *(const half4v*)(xpb + (size_t)td * GG);
    }

    float hlast = 0.f;
    #pragma unroll 4
    for (int t = 0; t < Tc; ++t) {
        const int s = t & 3;
        half4v p = pv[s];
        float aI = (float)p[0];
        float aF = (float)p[1];
        float aG = (float)p[2];
        float aO = (float)p[3];

        // refill slot s for t+4; no barrier/drain anywhere -> stays in flight
        {
            int tn = t + 4; if (tn >= Tc) tn = Tc - 1;
            pv[s] = *(const half4v*)(xpb + (size_t)tn * GG);
        }

        // h broadcast read. Single wave: DS pipe RAW vs previous iteration's
        // write is HW-ordered; hbuf[k] (runtime k) may-alias these reads so
        // the compiler keeps order and re-reads each step. wlds is a distinct
        // array -> weight loads hoistable without aliasing hbuf.
        half8v hv[7];
        #pragma unroll
        for (int j = 0; j < 7; ++j) hv[j] = *(half8v*)(hbuf + j * 8);

        #pragma unroll
        for (int j = 0; j < 7; ++j) {
            half2v* hp = (half2v*)&hv[j];
            const half2v* w0 = (const half2v*)&wr0[j];
            const half2v* w1 = (const half2v*)&wr1[j];
            const half2v* w2 = (const half2v*)&wr2[j];
            const half2v* w3 = (const half2v*)&wr3[j];
            #pragma unroll
            for (int q = 0; q < 4; ++q) {
                half2v hq = hp[q];
                aI = fdot2f(hq, w0[q], aI);
                aF = fdot2f(hq, w1[q], aF);
                aG = fdot2f(hq, w2[q], aG);
                aO = fdot2f(hq, w3[q], aO);
            }
        }
        float ii = fsig(aI), ff = fsig(aF), gg2 = ftanh(aG), oo = fsig(aO);
        c = ff * c + ii * gg2;
        float hn = oo * ftanh(c);
        if (k < HH) hbuf[k] = (_Float16)hn;
        hlast = hn;
    }
    if (k < HH) {
        hs[b * HH + k] = hlast;
        cs[b * HH + k] = c;
    }
}

// ---------------- Kernel 3: FC epilogue ----------------
__global__ __launch_bounds__(256) void fc_kernel(
    const float* __restrict__ hs, const float* __restrict__ W_fc,
    const float* __restrict__ b_fc, float* __restrict__ out)
{
    int idx = blockIdx.x * blockDim.x + threadIdx.x;   // 512*10
    if (idx < BB * 10) {
        int b = idx / 10, o = idx % 10;
        float a = b_fc[o];
        #pragma unroll
        for (int kx = 0; kx < HH; ++kx)
            a += hs[b * HH + kx] * W_fc[o * HH + kx];
        out[idx] = a;
    }
}

extern "C" void kernel_launch(void* const* d_in, const int* in_sizes, int n_in,
                              void* d_out, int out_size, void* d_ws, size_t ws_size,
                              hipStream_t stream)
{
    const float* x    = (const float*)d_in[0];
    const float* W_ih = (const float*)d_in[1];
    const float* W_hh = (const float*)d_in[2];
    const float* b_ih = (const float*)d_in[3];
    const float* b_hh = (const float*)d_in[4];
    const float* W_fc = (const float*)d_in[5];
    const float* b_fc = (const float*)d_in[6];
    float* out = (float*)d_out;
    char* wsb = (char*)d_ws;

    const size_t hs_b = (size_t)BB * HH * sizeof(float);        // 102400
    const size_t wfrags_b = (size_t)13 * 4 * 64 * 8 * 2;        // 53248
    const size_t whh_b = (size_t)GG * 56 * 2;                   // 22400
    const size_t bias_b = 1024;
    const size_t fixed_b = 2 * hs_b + wfrags_b + whh_b + bias_b;

    int Tc = TT;
    while (Tc > 64 && (size_t)BB * Tc * GG * 2 + fixed_b > ws_size)
        Tc >>= 1;
    int tsh = 0; { int v = Tc >> 6; while (v > 1) { v >>= 1; ++tsh; } }

    _Float16* xp16 = (_Float16*)wsb;
    char* p = wsb + (size_t)BB * Tc * GG * 2;
    float* hsbuf = (float*)p;            p += hs_b;
    float* csbuf = (float*)p;            p += hs_b;
    _Float16* wfrags = (_Float16*)p;     p += wfrags_b;
    _Float16* whh16 = (_Float16*)p;      p += whh_b;
    float* biasv = (float*)p;

    prep_kernel<<<25, 256, 0, stream>>>(W_ih, W_hh, b_ih, b_hh, wfrags, whh16, biasv);

    const int nch = TT / Tc;
    for (int j = 0; j < nch; ++j) {
        xproj_mfma<<<BB * (Tc >> 6), 256, 0, stream>>>(x, wfrags, biasv, xp16, j * Tc, tsh);
        lstm_rec<<<BB, 64, 0, stream>>>(xp16, whh16, hsbuf, csbuf, Tc, j == 0);
    }
    fc_kernel<<<(BB * 10 + 255) / 256, 256, 0, stream>>>(hsbuf, W_fc, b_fc, out);
}

// Round 4
// 464.533 us; speedup vs baseline: 1.9207x; 1.0177x over previous
//
#include <hip/hip_runtime.h>

// LSTM: B=512, T=512, I=128, H=50, O=10, fp32.
// R8: lstm_rec — kill the JIT hv reads. R7 evidence: VGPR=132 = 112 weights
//     + pv + misc, NO room for 28 hv regs -> compiler JIT-read each hv[j]
//     b128 right before use, exposing 7 x ~105cyc serial LDS latency
//     (420 VALU + 735 DS = 1155 ~= measured 1167 cyc/step).
//  - hv is now LOOP-CARRIED: read cluster placed right AFTER the hbuf write
//    at iteration bottom (same-wave DS pipe is in-order -> RAW safe, proven
//    R5-R7), feeding the next iteration through the back-edge phi. The
//    compiler cannot sink them; they issue as one pipelined burst and the
//    counted lgkmcnt wait at loop top overlaps with the xp unpack.
//  - h write unconditional: lanes>=50 (kk=0) write a finite duplicate of
//    unit 0's h into hbuf[50..63]; hv reads of [50..55] hit zero-padded
//    weight cols -> contribute exactly 0. No exec-mask divergence.
//  - Everything else identical to R7 (LDS-staged padded weights,
//    waves_per_eu(1,1), 4-deep xp prefetch, [b][t][unit*4+gate] layout).

#define BB 512
#define TT 512
#define II 128
#define HH 50
#define GG 200   // 4*H

typedef _Float16 half2v __attribute__((ext_vector_type(2)));
typedef _Float16 half4v __attribute__((ext_vector_type(4)));
typedef _Float16 half8v __attribute__((ext_vector_type(8)));
typedef float float4v __attribute__((ext_vector_type(4)));

#if defined(__has_builtin)
#if __has_builtin(__builtin_amdgcn_fdot2)
#define HAVE_FDOT2 1
#endif
#endif

__device__ __forceinline__ float fdot2f(half2v a, half2v b, float c) {
#ifdef HAVE_FDOT2
    return __builtin_amdgcn_fdot2(a, b, c, false);
#else
    return c + (float)a[0] * (float)b[0] + (float)a[1] * (float)b[1];
#endif
}

__device__ __forceinline__ float fsig(float x) {
    return 1.f / (1.f + __expf(-x));
}
__device__ __forceinline__ float ftanh(float x) {
    return 2.f * fsig(2.f * x) - 1.f;
}

// ---------------- Kernel 0: prep (once per launch) ----------------
// Gate permutation: gp = unit*4 + gate  <->  orig g = gate*50 + unit.
// wfrags: W_ih rows in PERMUTED order as f16 MFMA B-fragments
//         [nt 13][kc 4][lane 64][j 8]
// whh16:  W_hh rows padded to 56 f16, ORIGINAL order  [g 200][56]
// biasv:  b_ih + b_hh in PERMUTED order               [gp 200]
__global__ __launch_bounds__(256) void prep_kernel(
    const float* __restrict__ W_ih, const float* __restrict__ W_hh,
    const float* __restrict__ b_ih, const float* __restrict__ b_hh,
    _Float16* __restrict__ wfrags, _Float16* __restrict__ whh16,
    float* __restrict__ biasv)
{
    int idx = blockIdx.x * 256 + threadIdx.x;
    if (idx < 3328) {                       // 13*4*64 fragment slots
        int lane = idx & 63, kc = (idx >> 6) & 3, nt = idx >> 8;
        int gp = nt * 16 + (lane & 15);     // permuted gate index
        int k0 = kc * 32 + ((lane >> 4) & 3) * 8;
        half8v v;
        if (gp < GG) {
            int u = gp >> 2, j = gp & 3;
            const float* wr = W_ih + (size_t)(j * HH + u) * II + k0;
            #pragma unroll
            for (int q = 0; q < 8; ++q) v[q] = (_Float16)wr[q];
        } else {
            #pragma unroll
            for (int q = 0; q < 8; ++q) v[q] = (_Float16)0.f;
        }
        *(half8v*)(wfrags + (size_t)idx * 8) = v;
    } else if (idx < 3328 + 2800) {         // 200 rows * 14 quads
        int r = idx - 3328;
        int g = r / 14, j4 = r % 14;
        #pragma unroll
        for (int j = 0; j < 4; ++j) {
            int hidx = j4 * 4 + j;
            whh16[g * 56 + hidx] = (hidx < HH) ? (_Float16)W_hh[g * HH + hidx]
                                               : (_Float16)0.f;
        }
    } else if (idx < 3328 + 2800 + GG) {
        int gp = idx - 6128;
        int u = gp >> 2, j = gp & 3;
        biasv[gp] = b_ih[j * HH + u] + b_hh[j * HH + u];
    }
}

// ---------------- Kernel 1: xproj via MFMA, t-major tiles ----------------
// Block = (b, t-tile of 64). A = x[b][t0:t0+64][0:128] (contiguous 32KB).
// Output xp16[b][t - chunk][gp] f16, bias pre-added, coalesced 16B stores.
__global__ __launch_bounds__(256) void xproj_mfma(
    const float* __restrict__ x, const _Float16* __restrict__ wfrags,
    const float* __restrict__ biasv, _Float16* __restrict__ xp16,
    int t0, int tsh)
{
    __shared__ __align__(16) _Float16 afrag[4 * 4 * 64 * 8];  // 16 KB
    __shared__ __align__(16) _Float16 dtile[64 * GG];         // 25.6 KB
    const int tid = threadIdx.x;
    const int b = blockIdx.x >> tsh;
    const int tt = blockIdx.x & ((1 << tsh) - 1);
    const int trow0 = t0 + tt * 64;         // global t of tile row 0

    // Stage A: thread owns one fragment slot (16B): 2 float4 loads, 1 b128 write.
    // Wave reads 16 rows x 128B contiguous each -> full-cacheline coalescing.
    const float* xb = x + ((size_t)b * TT + trow0) * II;
    #pragma unroll
    for (int it = 0; it < 4; ++it) {
        int s = it * 256 + tid;             // slot in [0,1024)
        int l = s & 63, kc = (s >> 6) & 3, wq = s >> 8;
        int row = wq * 16 + (l & 15);
        int k0 = kc * 32 + ((l >> 4) & 3) * 8;
        const float4 v0 = *(const float4*)(xb + (size_t)row * II + k0);
        const float4 v1 = *(const float4*)(xb + (size_t)row * II + k0 + 4);
        half8v p;
        p[0] = (_Float16)v0.x; p[1] = (_Float16)v0.y;
        p[2] = (_Float16)v0.z; p[3] = (_Float16)v0.w;
        p[4] = (_Float16)v1.x; p[5] = (_Float16)v1.y;
        p[6] = (_Float16)v1.z; p[7] = (_Float16)v1.w;
        *(half8v*)(afrag + (size_t)s * 8) = p;
    }
    __syncthreads();

    const int w = tid >> 6;
    const int l = tid & 63;
    float4v acc[13];
    #pragma unroll
    for (int nt = 0; nt < 13; ++nt) acc[nt] = (float4v){0.f, 0.f, 0.f, 0.f};

    #pragma unroll
    for (int kc = 0; kc < 4; ++kc) {
        half8v a = *(half8v*)(afrag + (size_t)(((w * 4 + kc) * 64) + l) * 8);
        #pragma unroll
        for (int nt = 0; nt < 13; ++nt) {
            half8v bf = *(const half8v*)(wfrags + (size_t)(((nt * 4 + kc) * 64) + l) * 8);
            acc[nt] = __builtin_amdgcn_mfma_f32_16x16x32_f16(a, bf, acc[nt], 0, 0, 0);
        }
    }

    // D restage: col=lane&15 (permuted gate), row=(lane>>4)*4+reg (t-row).
    const int colb = l & 15, rq = l >> 4;
    #pragma unroll
    for (int nt = 0; nt < 13; ++nt) {
        int g = nt * 16 + colb;
        if (g < GG) {
            float bs = biasv[g];
            #pragma unroll
            for (int reg = 0; reg < 4; ++reg)
                dtile[(w * 16 + rq * 4 + reg) * GG + g] = (_Float16)(acc[nt][reg] + bs);
        }
    }
    __syncthreads();

    // Coalesced writeout: 64*200 f16 = 1600 x 16B contiguous.
    _Float16* outp = xp16 + ((size_t)b * (64 << tsh) + (size_t)tt * 64) * GG;
    #pragma unroll
    for (int it = 0; it < 7; ++it) {
        int idx = it * 256 + tid;
        if (idx < 1600) {
            float4v v = *(const float4v*)(dtile + (size_t)idx * 8);
            *(float4v*)(outp + (size_t)idx * 8) = v;
        }
    }
}

// ---------------- Kernel 2: recurrence (single wave, LDS weights) ---------
#define WSTR 58   // padded row stride in f16 (29 words -> coprime with 32 banks)

__global__
__attribute__((amdgpu_flat_work_group_size(64, 64)))
__attribute__((amdgpu_waves_per_eu(1, 1)))
void lstm_rec(
    const _Float16* __restrict__ xp16, const _Float16* __restrict__ whh16,
    float* __restrict__ hs, float* __restrict__ cs, int Tc, int first)
{
    __shared__ __align__(16) _Float16 wlds[GG * WSTR];   // 23.2 KB
    __shared__ __align__(16) _Float16 hbuf[64];
    const int b = blockIdx.x;
    const int k = threadIdx.x;
    const int kk = (k < HH) ? k : 0;

    // Stage W_hh (22.4 KB) into padded LDS: 1400 b128 slots, 22 per lane.
    for (int s = k; s < 1400; s += 64) {
        int g = s / 7, j = s % 7;
        float4v v = *(const float4v*)(whh16 + (size_t)g * 56 + j * 8);
        *(float4v*)(wlds + (size_t)g * WSTR + j * 8) = v;
    }

    float c = 0.f;
    _Float16 hinit = (_Float16)0.f;
    if (!first && k < HH) {
        c = cs[b * HH + k];
        hinit = (_Float16)hs[b * HH + k];
    }
    hbuf[k] = hinit;
    __syncthreads();   // staging + init visibility (once)

    // Hoisted weight loads: rows kk, kk+50, kk+100, kk+150 (7 b128 each).
    // waves_per_eu(1,1): 512-VGPR budget, no occupancy pressure -> resident
    // (R7 verified: VGPR=132 = weights resident).
    float4v wr0[7], wr1[7], wr2[7], wr3[7];
    #pragma unroll
    for (int j = 0; j < 7; ++j) {
        wr0[j] = *(const float4v*)(wlds + (size_t)(kk      ) * WSTR + j * 8);
        wr1[j] = *(const float4v*)(wlds + (size_t)(kk +  50) * WSTR + j * 8);
        wr2[j] = *(const float4v*)(wlds + (size_t)(kk + 100) * WSTR + j * 8);
        wr3[j] = *(const float4v*)(wlds + (size_t)(kk + 150) * WSTR + j * 8);
    }

    // xp: [b][t][unit*4+gate] -> one 8B load per step, 4-deep prefetch.
    const _Float16* xpb = xp16 + (size_t)b * Tc * GG + kk * 4;
    half4v pv[4];
    #pragma unroll
    for (int d = 0; d < 4; ++d) {
        int td = (d < Tc) ? d : (Tc - 1);
        pv[d] = *(const half4v*)(xpb + (size_t)td * GG);
    }

    // Loop-carried h fragments: initial read, then re-read at iteration
    // BOTTOM right after the write (clustered, pipelined; cannot be sunk).
    half8v hv[7];
    #pragma unroll
    for (int j = 0; j < 7; ++j) hv[j] = *(half8v*)(hbuf + j * 8);

    float hlast = 0.f;
    #pragma unroll 4
    for (int t = 0; t < Tc; ++t) {
        const int s = t & 3;
        half4v p = pv[s];
        float aI = (float)p[0];
        float aF = (float)p[1];
        float aG = (float)p[2];
        float aO = (float)p[3];

        // refill slot s for t+4; no barrier/drain anywhere -> stays in flight
        {
            int tn = t + 4; if (tn >= Tc) tn = Tc - 1;
            pv[s] = *(const half4v*)(xpb + (size_t)tn * GG);
        }

        #pragma unroll
        for (int j = 0; j < 7; ++j) {
            half2v* hp = (half2v*)&hv[j];
            const half2v* w0 = (const half2v*)&wr0[j];
            const half2v* w1 = (const half2v*)&wr1[j];
            const half2v* w2 = (const half2v*)&wr2[j];
            const half2v* w3 = (const half2v*)&wr3[j];
            #pragma unroll
            for (int q = 0; q < 4; ++q) {
                half2v hq = hp[q];
                aI = fdot2f(hq, w0[q], aI);
                aF = fdot2f(hq, w1[q], aF);
                aG = fdot2f(hq, w2[q], aG);
                aO = fdot2f(hq, w3[q], aO);
            }
        }
        float ii = fsig(aI), ff = fsig(aF), gg2 = ftanh(aG), oo = fsig(aO);
        c = ff * c + ii * gg2;
        float hn = oo * ftanh(c);

        // Unconditional write: lanes>=50 (kk=0) store a finite duplicate of
        // h_0 into hbuf[50..63]; reads of [50..55] hit zero weight cols.
        hbuf[k] = (_Float16)hn;
        // Clustered re-read for next iteration. Same-wave DS pipe is
        // in-order -> write-then-read RAW is safe without any wait; the
        // counted lgkmcnt before first use lands at next loop top, with
        // the xp unpack overlapping the latency.
        #pragma unroll
        for (int j = 0; j < 7; ++j) hv[j] = *(half8v*)(hbuf + j * 8);

        hlast = hn;
    }
    if (k < HH) {
        hs[b * HH + k] = hlast;
        cs[b * HH + k] = c;
    }
}

// ---------------- Kernel 3: FC epilogue ----------------
__global__ __launch_bounds__(256) void fc_kernel(
    const float* __restrict__ hs, const float* __restrict__ W_fc,
    const float* __restrict__ b_fc, float* __restrict__ out)
{
    int idx = blockIdx.x * blockDim.x + threadIdx.x;   // 512*10
    if (idx < BB * 10) {
        int b = idx / 10, o = idx % 10;
        float a = b_fc[o];
        #pragma unroll
        for (int kx = 0; kx < HH; ++kx)
            a += hs[b * HH + kx] * W_fc[o * HH + kx];
        out[idx] = a;
    }
}

extern "C" void kernel_launch(void* const* d_in, const int* in_sizes, int n_in,
                              void* d_out, int out_size, void* d_ws, size_t ws_size,
                              hipStream_t stream)
{
    const float* x    = (const float*)d_in[0];
    const float* W_ih = (const float*)d_in[1];
    const float* W_hh = (const float*)d_in[2];
    const float* b_ih = (const float*)d_in[3];
    const float* b_hh = (const float*)d_in[4];
    const float* W_fc = (const float*)d_in[5];
    const float* b_fc = (const float*)d_in[6];
    float* out = (float*)d_out;
    char* wsb = (char*)d_ws;

    const size_t hs_b = (size_t)BB * HH * sizeof(float);        // 102400
    const size_t wfrags_b = (size_t)13 * 4 * 64 * 8 * 2;        // 53248
    const size_t whh_b = (size_t)GG * 56 * 2;                   // 22400
    const size_t bias_b = 1024;
    const size_t fixed_b = 2 * hs_b + wfrags_b + whh_b + bias_b;

    int Tc = TT;
    while (Tc > 64 && (size_t)BB * Tc * GG * 2 + fixed_b > ws_size)
        Tc >>= 1;
    int tsh = 0; { int v = Tc >> 6; while (v > 1) { v >>= 1; ++tsh; } }

    _Float16* xp16 = (_Float16*)wsb;
    char* p = wsb + (size_t)BB * Tc * GG * 2;
    float* hsbuf = (float*)p;            p += hs_b;
    float* csbuf = (float*)p;            p += hs_b;
    _Float16* wfrags = (_Float16*)p;     p += wfrags_b;
    _Float16* whh16 = (_Float16*)p;      p += whh_b;
    float* biasv = (float*)p;

    prep_kernel<<<25, 256, 0, stream>>>(W_ih, W_hh, b_ih, b_hh, wfrags, whh16, biasv);

    const int nch = TT / Tc;
    for (int j = 0; j < nch; ++j) {
        xproj_mfma<<<BB * (Tc >> 6), 256, 0, stream>>>(x, wfrags, biasv, xp16, j * Tc, tsh);
        lstm_rec<<<BB, 64, 0, stream>>>(xp16, whh16, hsbuf, csbuf, Tc, j == 0);
    }
    fc_kernel<<<(BB * 10 + 255) / 256, 256, 0, stream>>>(hsbuf, W_fc, b_fc, out);
}

// Round 5
// 452.141 us; speedup vs baseline: 1.9734x; 1.0274x over previous
//
#include <hip/hip_runtime.h>

// LSTM: B=512, T=512, I=128, H=50, O=10, fp32.
// R9: xproj rewritten (lstm_rec untouched — R8 showed its remaining stalls
//     need disasm; and "rest" ≈ 195µs is xproj vs a 37µs HBM roofline).
//  Old xproj: 4096 tiny blocks; B-fragments re-read from GLOBAL per MFMA
//  phase (52 latency-exposed L2 loads/wave/tile); A staged through LDS for
//  no reason (thread's consumed fragment = a directly loadable 32B chunk,
//  and lanes {l,l+16,l+32,l+48} cover a full 128B line per row -> coalesced).
//  New xproj: 1 block per batch (512 blocks, 2/CU at 79.6KB LDS), 8 t-tiles
//  per block. wfrags staged ONCE to LDS (linear ds_read_b128, conflict-free);
//  A-fragments loaded straight into registers, next tile prefetched into
//  regs under the MFMA phase; dtile restage kept for coalesced 16B stores.
//  Barriers: 2/tile (dtile reuse protection only).

#define BB 512
#define TT 512
#define II 128
#define HH 50
#define GG 200   // 4*H

typedef _Float16 half2v __attribute__((ext_vector_type(2)));
typedef _Float16 half4v __attribute__((ext_vector_type(4)));
typedef _Float16 half8v __attribute__((ext_vector_type(8)));
typedef float float4v __attribute__((ext_vector_type(4)));

#if defined(__has_builtin)
#if __has_builtin(__builtin_amdgcn_fdot2)
#define HAVE_FDOT2 1
#endif
#endif

__device__ __forceinline__ float fdot2f(half2v a, half2v b, float c) {
#ifdef HAVE_FDOT2
    return __builtin_amdgcn_fdot2(a, b, c, false);
#else
    return c + (float)a[0] * (float)b[0] + (float)a[1] * (float)b[1];
#endif
}

__device__ __forceinline__ float fsig(float x) {
    return 1.f / (1.f + __expf(-x));
}
__device__ __forceinline__ float ftanh(float x) {
    return 2.f * fsig(2.f * x) - 1.f;
}

// ---------------- Kernel 0: prep (once per launch) ----------------
// Gate permutation: gp = unit*4 + gate  <->  orig g = gate*50 + unit.
// wfrags: W_ih rows in PERMUTED order as f16 MFMA B-fragments
//         [nt 13][kc 4][lane 64][j 8]
// whh16:  W_hh rows padded to 56 f16, ORIGINAL order  [g 200][56]
// biasv:  b_ih + b_hh in PERMUTED order               [gp 200]
__global__ __launch_bounds__(256) void prep_kernel(
    const float* __restrict__ W_ih, const float* __restrict__ W_hh,
    const float* __restrict__ b_ih, const float* __restrict__ b_hh,
    _Float16* __restrict__ wfrags, _Float16* __restrict__ whh16,
    float* __restrict__ biasv)
{
    int idx = blockIdx.x * 256 + threadIdx.x;
    if (idx < 3328) {                       // 13*4*64 fragment slots
        int lane = idx & 63, kc = (idx >> 6) & 3, nt = idx >> 8;
        int gp = nt * 16 + (lane & 15);     // permuted gate index
        int k0 = kc * 32 + ((lane >> 4) & 3) * 8;
        half8v v;
        if (gp < GG) {
            int u = gp >> 2, j = gp & 3;
            const float* wr = W_ih + (size_t)(j * HH + u) * II + k0;
            #pragma unroll
            for (int q = 0; q < 8; ++q) v[q] = (_Float16)wr[q];
        } else {
            #pragma unroll
            for (int q = 0; q < 8; ++q) v[q] = (_Float16)0.f;
        }
        *(half8v*)(wfrags + (size_t)idx * 8) = v;
    } else if (idx < 3328 + 2800) {         // 200 rows * 14 quads
        int r = idx - 3328;
        int g = r / 14, j4 = r % 14;
        #pragma unroll
        for (int j = 0; j < 4; ++j) {
            int hidx = j4 * 4 + j;
            whh16[g * 56 + hidx] = (hidx < HH) ? (_Float16)W_hh[g * HH + hidx]
                                               : (_Float16)0.f;
        }
    } else if (idx < 3328 + 2800 + GG) {
        int gp = idx - 6128;
        int u = gp >> 2, j = gp & 3;
        biasv[gp] = b_ih[j * HH + u] + b_hh[j * HH + u];
    }
}

// ---------------- Kernel 1: xproj via MFMA, batch-per-block ----------------
// Block = batch b; loops ntile (=Tc/64) t-tiles. wfrags in LDS (staged once),
// A-fragments direct-to-register (coalesced: 4 lanes/row cover one 128B line),
// next-tile A prefetched into regs under MFMA. Output xp16[b][t_local][gp].
__global__ __launch_bounds__(256) void xproj_mfma(
    const float* __restrict__ x, const _Float16* __restrict__ wfrags,
    const float* __restrict__ biasv, _Float16* __restrict__ xp16,
    int t0, int ntile)
{
    __shared__ __align__(16) _Float16 wflds[3328 * 8];   // 53248 B
    __shared__ __align__(16) _Float16 dtile[64 * GG];    // 25600 B
    __shared__ float blds[GG];                           // 800 B  -> 79.6 KB
    const int tid = threadIdx.x;
    const int b = blockIdx.x;
    const int w = tid >> 6, l = tid & 63;

    // Stage W_ih fragments (53KB) + bias once per block (linear b128, no conflicts).
    for (int s = tid; s < 3328; s += 256)
        *(float4v*)(wflds + (size_t)s * 8) = *(const float4v*)(wfrags + (size_t)s * 8);
    for (int s = tid; s < GG; s += 256) blds[s] = biasv[s];

    // Per-thread A-fragment source: row = w*16 + (l&15), 8-float chunk (l>>4)&3.
    const int row = w * 16 + (l & 15);
    const int kq = (l >> 4) & 3;
    const float* xbase = x + ((size_t)b * TT + (size_t)t0 + row) * II + kq * 8;

    // Prologue: tile 0 A-fragments (4 kc x 32B = 8 float4).
    float4 f0[4], f1[4];
    #pragma unroll
    for (int kc = 0; kc < 4; ++kc) {
        f0[kc] = *(const float4*)(xbase + kc * 32);
        f1[kc] = *(const float4*)(xbase + kc * 32 + 4);
    }
    __syncthreads();   // wflds/blds ready

    const int colb = l & 15, rq = l >> 4;

    for (int tt = 0; tt < ntile; ++tt) {
        // Convert this tile's A-regs to half8 fragments.
        half8v a[4];
        #pragma unroll
        for (int kc = 0; kc < 4; ++kc) {
            a[kc][0] = (_Float16)f0[kc].x; a[kc][1] = (_Float16)f0[kc].y;
            a[kc][2] = (_Float16)f0[kc].z; a[kc][3] = (_Float16)f0[kc].w;
            a[kc][4] = (_Float16)f1[kc].x; a[kc][5] = (_Float16)f1[kc].y;
            a[kc][6] = (_Float16)f1[kc].z; a[kc][7] = (_Float16)f1[kc].w;
        }
        // Prefetch next tile's A into regs; completes under MFMA phase.
        if (tt + 1 < ntile) {
            const float* xn = xbase + (size_t)(tt + 1) * 64 * II;
            #pragma unroll
            for (int kc = 0; kc < 4; ++kc) {
                f0[kc] = *(const float4*)(xn + kc * 32);
                f1[kc] = *(const float4*)(xn + kc * 32 + 4);
            }
        }

        float4v acc[13];
        #pragma unroll
        for (int nt = 0; nt < 13; ++nt) acc[nt] = (float4v){0.f, 0.f, 0.f, 0.f};
        #pragma unroll
        for (int kc = 0; kc < 4; ++kc) {
            #pragma unroll
            for (int nt = 0; nt < 13; ++nt) {
                half8v bf = *(const half8v*)(wflds + (size_t)(((nt * 4 + kc) * 64) + l) * 8);
                acc[nt] = __builtin_amdgcn_mfma_f32_16x16x32_f16(a[kc], bf, acc[nt], 0, 0, 0);
            }
        }

        // Protect dtile from previous tile's writeout readers, then restage.
        __syncthreads();
        #pragma unroll
        for (int nt = 0; nt < 13; ++nt) {
            int g = nt * 16 + colb;
            if (g < GG) {
                float bs = blds[g];
                #pragma unroll
                for (int reg = 0; reg < 4; ++reg)
                    dtile[(w * 16 + rq * 4 + reg) * GG + g] = (_Float16)(acc[nt][reg] + bs);
            }
        }
        __syncthreads();

        // Coalesced writeout: 64*200 f16 = 1600 x 16B contiguous.
        _Float16* outp = xp16 + ((size_t)b * ntile + tt) * 64 * GG;
        #pragma unroll
        for (int it = 0; it < 7; ++it) {
            int idx = it * 256 + tid;
            if (idx < 1600) {
                float4v v = *(const float4v*)(dtile + (size_t)idx * 8);
                *(float4v*)(outp + (size_t)idx * 8) = v;
            }
        }
    }
}

// ---------------- Kernel 2: recurrence (single wave, LDS weights) ---------
#define WSTR 58   // padded row stride in f16 (29 words -> coprime with 32 banks)

__global__
__attribute__((amdgpu_flat_work_group_size(64, 64)))
__attribute__((amdgpu_waves_per_eu(1, 1)))
void lstm_rec(
    const _Float16* __restrict__ xp16, const _Float16* __restrict__ whh16,
    float* __restrict__ hs, float* __restrict__ cs, int Tc, int first)
{
    __shared__ __align__(16) _Float16 wlds[GG * WSTR];   // 23.2 KB
    __shared__ __align__(16) _Float16 hbuf[64];
    const int b = blockIdx.x;
    const int k = threadIdx.x;
    const int kk = (k < HH) ? k : 0;

    // Stage W_hh (22.4 KB) into padded LDS: 1400 b128 slots, 22 per lane.
    for (int s = k; s < 1400; s += 64) {
        int g = s / 7, j = s % 7;
        float4v v = *(const float4v*)(whh16 + (size_t)g * 56 + j * 8);
        *(float4v*)(wlds + (size_t)g * WSTR + j * 8) = v;
    }

    float c = 0.f;
    _Float16 hinit = (_Float16)0.f;
    if (!first && k < HH) {
        c = cs[b * HH + k];
        hinit = (_Float16)hs[b * HH + k];
    }
    hbuf[k] = hinit;
    __syncthreads();   // staging + init visibility (once)

    // Hoisted weight loads: rows kk, kk+50, kk+100, kk+150 (7 b128 each).
    float4v wr0[7], wr1[7], wr2[7], wr3[7];
    #pragma unroll
    for (int j = 0; j < 7; ++j) {
        wr0[j] = *(const float4v*)(wlds + (size_t)(kk      ) * WSTR + j * 8);
        wr1[j] = *(const float4v*)(wlds + (size_t)(kk +  50) * WSTR + j * 8);
        wr2[j] = *(const float4v*)(wlds + (size_t)(kk + 100) * WSTR + j * 8);
        wr3[j] = *(const float4v*)(wlds + (size_t)(kk + 150) * WSTR + j * 8);
    }

    // xp: [b][t][unit*4+gate] -> one 8B load per step, 4-deep prefetch.
    const _Float16* xpb = xp16 + (size_t)b * Tc * GG + kk * 4;
    half4v pv[4];
    #pragma unroll
    for (int d = 0; d < 4; ++d) {
        int td = (d < Tc) ? d : (Tc - 1);
        pv[d] = *(const half4v*)(xpb + (size_t)td * GG);
    }

    // Loop-carried h fragments: initial read, then re-read at iteration
    // bottom right after the write.
    half8v hv[7];
    #pragma unroll
    for (int j = 0; j < 7; ++j) hv[j] = *(half8v*)(hbuf + j * 8);

    float hlast = 0.f;
    #pragma unroll 4
    for (int t = 0; t < Tc; ++t) {
        const int s = t & 3;
        half4v p = pv[s];
        float aI = (float)p[0];
        float aF = (float)p[1];
        float aG = (float)p[2];
        float aO = (float)p[3];

        // refill slot s for t+4; no barrier/drain anywhere -> stays in flight
        {
            int tn = t + 4; if (tn >= Tc) tn = Tc - 1;
            pv[s] = *(const half4v*)(xpb + (size_t)tn * GG);
        }

        #pragma unroll
        for (int j = 0; j < 7; ++j) {
            half2v* hp = (half2v*)&hv[j];
            const half2v* w0 = (const half2v*)&wr0[j];
            const half2v* w1 = (const half2v*)&wr1[j];
            const half2v* w2 = (const half2v*)&wr2[j];
            const half2v* w3 = (const half2v*)&wr3[j];
            #pragma unroll
            for (int q = 0; q < 4; ++q) {
                half2v hq = hp[q];
                aI = fdot2f(hq, w0[q], aI);
                aF = fdot2f(hq, w1[q], aF);
                aG = fdot2f(hq, w2[q], aG);
                aO = fdot2f(hq, w3[q], aO);
            }
        }
        float ii = fsig(aI), ff = fsig(aF), gg2 = ftanh(aG), oo = fsig(aO);
        c = ff * c + ii * gg2;
        float hn = oo * ftanh(c);

        hbuf[k] = (_Float16)hn;
        #pragma unroll
        for (int j = 0; j < 7; ++j) hv[j] = *(half8v*)(hbuf + j * 8);

        hlast = hn;
    }
    if (k < HH) {
        hs[b * HH + k] = hlast;
        cs[b * HH + k] = c;
    }
}

// ---------------- Kernel 3: FC epilogue ----------------
__global__ __launch_bounds__(256) void fc_kernel(
    const float* __restrict__ hs, const float* __restrict__ W_fc,
    const float* __restrict__ b_fc, float* __restrict__ out)
{
    int idx = blockIdx.x * blockDim.x + threadIdx.x;   // 512*10
    if (idx < BB * 10) {
        int b = idx / 10, o = idx % 10;
        float a = b_fc[o];
        #pragma unroll
        for (int kx = 0; kx < HH; ++kx)
            a += hs[b * HH + kx] * W_fc[o * HH + kx];
        out[idx] = a;
    }
}

extern "C" void kernel_launch(void* const* d_in, const int* in_sizes, int n_in,
                              void* d_out, int out_size, void* d_ws, size_t ws_size,
                              hipStream_t stream)
{
    const float* x    = (const float*)d_in[0];
    const float* W_ih = (const float*)d_in[1];
    const float* W_hh = (const float*)d_in[2];
    const float* b_ih = (const float*)d_in[3];
    const float* b_hh = (const float*)d_in[4];
    const float* W_fc = (const float*)d_in[5];
    const float* b_fc = (const float*)d_in[6];
    float* out = (float*)d_out;
    char* wsb = (char*)d_ws;

    const size_t hs_b = (size_t)BB * HH * sizeof(float);        // 102400
    const size_t wfrags_b = (size_t)13 * 4 * 64 * 8 * 2;        // 53248
    const size_t whh_b = (size_t)GG * 56 * 2;                   // 22400
    const size_t bias_b = 1024;
    const size_t fixed_b = 2 * hs_b + wfrags_b + whh_b + bias_b;

    int Tc = TT;
    while (Tc > 64 && (size_t)BB * Tc * GG * 2 + fixed_b > ws_size)
        Tc >>= 1;

    _Float16* xp16 = (_Float16*)wsb;
    char* p = wsb + (size_t)BB * Tc * GG * 2;
    float* hsbuf = (float*)p;            p += hs_b;
    float* csbuf = (float*)p;            p += hs_b;
    _Float16* wfrags = (_Float16*)p;     p += wfrags_b;
    _Float16* whh16 = (_Float16*)p;      p += whh_b;
    float* biasv = (float*)p;

    prep_kernel<<<25, 256, 0, stream>>>(W_ih, W_hh, b_ih, b_hh, wfrags, whh16, biasv);

    const int nch = TT / Tc;
    for (int j = 0; j < nch; ++j) {
        xproj_mfma<<<BB, 256, 0, stream>>>(x, wfrags, biasv, xp16, j * Tc, Tc >> 6);
        lstm_rec<<<BB, 64, 0, stream>>>(xp16, whh16, hsbuf, csbuf, Tc, j == 0);
    }
    fc_kernel<<<(BB * 10 + 255) / 256, 256, 0, stream>>>(hsbuf, W_fc, b_fc, out);
}